// Round 4
// baseline (230.630 us; speedup 1.0000x reference)
//
#include <hip/hip_runtime.h>

// Sparsemax over last axis of (16, 2048, 1024) fp32.
// One wave per row, 16 elems/lane in registers.
//
// Key bound: (z_max - tau*)+ <= sum_i (z_i - tau*)+ = 1  =>  tau* >= max - 1.
// So Newton/Michelot started at tau0 = max - 1 begins with the true support's
// superset {z > max-1} (tiny for Gaussian rows) and converges in ~3-5 steps,
// vs ~10 from the full active set. Counts via __ballot/popcll (scalar pipe),
// only the float sum needs a shuffle reduction.
//
// Persistent grid (2048 blocks = 8/CU, fully resident), 4 rows/wave with
// software prefetch of the next row to keep the memory pipe saturated.

typedef float f32x4 __attribute__((ext_vector_type(4)));  // native vector: OK for
                                                          // __builtin_nontemporal_store

constexpr int N      = 1024;
constexpr int ROWS   = 16 * 2048;   // 32768
constexpr int NBLK   = 2048;
constexpr int NWAVES = NBLK * 4;    // 8192
constexpr int RPW    = ROWS / NWAVES;  // 4 rows per wave (exact)

__global__ __launch_bounds__(256, 8) void sparsemax_kernel(const float* __restrict__ x,
                                                           float* __restrict__ out) {
    const int wid  = threadIdx.x >> 6;
    const int lane = threadIdx.x & 63;
    const int wave = (int)blockIdx.x * 4 + wid;

    const f32x4* __restrict__ xv = reinterpret_cast<const f32x4*>(x);
    f32x4* __restrict__ ov       = reinterpret_cast<f32x4*>(out);

    // Prime the pipeline: row 'wave'.
    f32x4 cur[4];
    {
        const long long base = (long long)wave * 256 + lane;
        #pragma unroll
        for (int j = 0; j < 4; ++j) cur[j] = xv[base + 64 * j];
    }

    #pragma unroll
    for (int t = 0; t < RPW; ++t) {
        const int row = wave + t * NWAVES;

        // Prefetch next row before touching this row's reduction chains.
        f32x4 nxt[4];
        if (t + 1 < RPW) {
            const long long nb = (long long)(wave + (t + 1) * NWAVES) * 256 + lane;
            #pragma unroll
            for (int j = 0; j < 4; ++j) nxt[j] = xv[nb + 64 * j];
        }

        float z[16];
        #pragma unroll
        for (int j = 0; j < 4; ++j) {
            z[4 * j + 0] = cur[j].x; z[4 * j + 1] = cur[j].y;
            z[4 * j + 2] = cur[j].z; z[4 * j + 3] = cur[j].w;
        }

        // Wave-wide row max.
        float m = z[0];
        #pragma unroll
        for (int i = 1; i < 16; ++i) m = fmaxf(m, z[i]);
        #pragma unroll
        for (int o = 1; o < 64; o <<= 1) m = fmaxf(m, __shfl_xor(m, o, 64));

        // Newton (Michelot) from the provable lower bound tau0 = max - 1.
        // Active sets are nested & strictly shrinking => equal count == fixed point.
        float tau   = m - 1.0f;
        int   kprev = N + 1;
        for (int it = 0; it < 64; ++it) {
            float ls = 0.f;
            int   lc = 0;
            #pragma unroll
            for (int i = 0; i < 16; ++i) {
                const bool p = z[i] > tau;
                lc += (int)__popcll(__ballot(p));   // wave-uniform count, SALU
                ls += p ? z[i] : 0.0f;
            }
            #pragma unroll
            for (int o = 1; o < 64; o <<= 1) ls += __shfl_xor(ls, o, 64);
            const float tn = (ls - 1.0f) * __builtin_amdgcn_rcpf((float)lc);
            if (lc >= kprev) break;   // set stable -> tau already exact
            kprev = lc;
            tau   = tn;
        }

        // Emit: non-temporal stores (pure stream, keep L2/L3 for input).
        const long long ob = (long long)row * 256 + lane;
        #pragma unroll
        for (int j = 0; j < 4; ++j) {
            f32x4 o4;
            o4.x = fmaxf(z[4 * j + 0] - tau, 0.f);
            o4.y = fmaxf(z[4 * j + 1] - tau, 0.f);
            o4.z = fmaxf(z[4 * j + 2] - tau, 0.f);
            o4.w = fmaxf(z[4 * j + 3] - tau, 0.f);
            __builtin_nontemporal_store(o4, &ov[ob + 64 * j]);
        }

        if (t + 1 < RPW) {
            #pragma unroll
            for (int j = 0; j < 4; ++j) cur[j] = nxt[j];
        }
    }
}

extern "C" void kernel_launch(void* const* d_in, const int* in_sizes, int n_in,
                              void* d_out, int out_size, void* d_ws, size_t ws_size,
                              hipStream_t stream) {
    const float* x   = (const float*)d_in[0];
    float*       out = (float*)d_out;
    hipLaunchKernelGGL(sparsemax_kernel, dim3(NBLK), dim3(256), 0, stream, x, out);
}